// Round 14
// baseline (247.187 us; speedup 1.0000x reference)
//
#include <hip/hip_runtime.h>

// Problem constants
#define BB 4
#define NN 1024
#define FF 512
#define HH 8
#define DD 64
#define EE 16

typedef unsigned short u16;
typedef _Float16 f16;
typedef __attribute__((ext_vector_type(8))) _Float16 f16x8;
typedef __attribute__((ext_vector_type(4))) _Float16 f16x4;
typedef __attribute__((ext_vector_type(4))) float     f32x4;

#define MFMAH(a,b,c) __builtin_amdgcn_mfma_f32_16x16x32_f16((a),(b),(c),0,0,0)

static __device__ __forceinline__ void gld16(const void* g, void* l){
  __builtin_amdgcn_global_load_lds((const __attribute__((address_space(1))) unsigned int*)g,
                                   (__attribute__((address_space(3))) unsigned int*)l, 16, 0, 0);
}

// ---------------------------------------------------------------------------
// K0: transpose weights -> f16. [Wq|Wk|Wv] (512f x 1536c) -> WT [c][f];
// Wo -> WoT [c][f].
__global__ __launch_bounds__(256) void k_wsplit(
    const float* __restrict__ Wq, const float* __restrict__ Wk,
    const float* __restrict__ Wv, const float* __restrict__ Wo,
    f16* __restrict__ WT, f16* __restrict__ WoT){
  __shared__ float tile[32][33];
  int bid = blockIdx.x, t = threadIdx.x;
  int isA = bid < 768;
  int tb  = isA ? bid : bid - 768;
  int nct = isA ? 48 : 16;
  int ct = tb % nct, ft = tb / nct;
  int c0 = ct * 32, f0 = ft * 32;
  #pragma unroll
  for (int r4 = 0; r4 < 4; r4++){
    int fl = (t >> 5) * 4 + r4, cl = t & 31;
    int f = f0 + fl, c = c0 + cl;
    float v;
    if (isA){
      const float* W = (c < 512) ? Wq : ((c < 1024) ? Wk : Wv);
      v = W[f * 512 + (c & 511)];
    } else {
      v = Wo[f * 512 + c];
    }
    tile[fl][cl] = v;
  }
  __syncthreads();
  #pragma unroll
  for (int r4 = 0; r4 < 4; r4++){
    int cl = (t >> 5) * 4 + r4, fl = t & 31;
    float v = tile[fl][cl];
    int c = c0 + cl, f = f0 + fl;
    if (isA) WT[c * 512 + f]  = (f16)v;
    else     WoT[c * 512 + f] = (f16)v;
  }
}

// ---------------------------------------------------------------------------
// K1: LayerNorm (fp32) -> r as f16. One wave per row.
__global__ __launch_bounds__(256) void k_ln(
    const float* __restrict__ x, const float* __restrict__ gamma,
    const float* __restrict__ beta, f16* __restrict__ rf){
  int row  = blockIdx.x * 4 + (threadIdx.x >> 6);
  int lane = threadIdx.x & 63;
  const float* px = x + (size_t)row * 512 + lane * 8;
  float4 a = *(const float4*)px;
  float4 b = *(const float4*)(px + 4);
  float v[8] = {a.x,a.y,a.z,a.w,b.x,b.y,b.z,b.w};
  float s = 0.f, q = 0.f;
  #pragma unroll
  for (int j = 0; j < 8; j++){ s += v[j]; q += v[j]*v[j]; }
  #pragma unroll
  for (int m = 1; m < 64; m <<= 1){ s += __shfl_xor(s, m, 64); q += __shfl_xor(q, m, 64); }
  float mean = s * (1.f/512.f);
  float var  = q * (1.f/512.f) - mean * mean;
  float rstd = rsqrtf(var + 1e-5f);
  float4 ga = *(const float4*)(gamma + lane*8);
  float4 gb = *(const float4*)(gamma + lane*8 + 4);
  float4 b0 = *(const float4*)(beta  + lane*8);
  float4 b1 = *(const float4*)(beta  + lane*8 + 4);
  float gs[8] = {ga.x,ga.y,ga.z,ga.w,gb.x,gb.y,gb.z,gb.w};
  float bs[8] = {b0.x,b0.y,b0.z,b0.w,b1.x,b1.y,b1.z,b1.w};
  f16x8 hv;
  #pragma unroll
  for (int j = 0; j < 8; j++){
    float r = (v[j] - mean) * rstd * gs[j] + bs[j];
    hv[j] = (f16)r;
  }
  *(f16x8*)(rf + (size_t)row * 512 + lane * 8) = hv;
}

// ---------------------------------------------------------------------------
// K2: QKV projection GEMM, f16 single-pass, 128x128 tile BK=32.
__global__ __launch_bounds__(256) void k_qkv(
    const f16* __restrict__ rf, const f16* __restrict__ WT,
    f16* __restrict__ qf, f16* __restrict__ kf, f16* __restrict__ vT){
  __shared__ f16 As[128*32], Bs[128*32];
  int bid = blockIdx.x;
  int mt = bid & 31, nt = bid >> 5;
  int m0 = mt << 7,  n0 = nt << 7;
  int t = threadIdx.x, lane = t & 63, w = t >> 6;
  int wm = (w >> 1) << 6, wn = (w & 1) << 6;
  int fr = lane & 15, g = lane >> 4;
  f32x4 acc[4][4];
  #pragma unroll
  for (int i = 0; i < 4; i++)
    #pragma unroll
    for (int j = 0; j < 4; j++) acc[i][j] = (f32x4){0.f,0.f,0.f,0.f};

  for (int k0 = 0; k0 < 512; k0 += 32){
    #pragma unroll
    for (int q = 0; q < 2; q++){
      int c = ((q << 2) + w) * 64 + lane;
      int row = c >> 2, part = c & 3;
      int ldso = ((q << 2) + w) * 512;
      gld16(rf + (size_t)(m0+row)*512 + k0 + part*8, &As[ldso]);
      gld16(WT + (size_t)(n0+row)*512 + k0 + part*8, &Bs[ldso]);
    }
    __syncthreads();
    f16x8 a[4], b[4];
    #pragma unroll
    for (int mi = 0; mi < 4; mi++) a[mi] = *(const f16x8*)&As[(wm + mi*16 + fr)*32 + g*8];
    #pragma unroll
    for (int ni = 0; ni < 4; ni++) b[ni] = *(const f16x8*)&Bs[(wn + ni*16 + fr)*32 + g*8];
    #pragma unroll
    for (int mi = 0; mi < 4; mi++)
      #pragma unroll
      for (int ni = 0; ni < 4; ni++)
        acc[mi][ni] = MFMAH(a[mi], b[ni], acc[mi][ni]);
    __syncthreads();
  }
  #pragma unroll
  for (int mi = 0; mi < 4; mi++)
    #pragma unroll
    for (int ni = 0; ni < 4; ni++)
      #pragma unroll
      for (int r = 0; r < 4; r++){
        int gm = m0 + wm + mi*16 + g*4 + r;
        int gc = n0 + wn + ni*16 + fr;
        float vv = acc[mi][ni][r];
        int b = gm >> 10, i = gm & 1023;
        int mat = gc >> 9, h = (gc >> 6) & 7, d = gc & 63;
        size_t idx = ((size_t)((b << 3) + h) * 1024 + i) * 64 + d;
        if      (mat == 0) qf[idx] = (f16)vv;
        else if (mat == 1) kf[idx] = (f16)vv;
        else vT[((size_t)((b << 3) + h) * 64 + d) * 1024 + i] = (f16)vv;
      }
}

// ---------------------------------------------------------------------------
// K3: fused attention v5 — bias computed INLINE from edge (biasP eliminated).
// Block = (b, it, s): 512 blocks x 512 thr = 8 free-running head-waves (no
// block barriers). Per jt tile: wave quad-coop loads the 32KB edge tile
// (1KB-coalesced; 8 waves share via L1/L2 — edge HBM read exactly once),
// computes its head's bias (4 FMA + 2 quad shfl per 16B chunk), stages into
// parity-dbuf wave-private LDS in fragment order, then QK MFMA + online
// softmax + PV exactly as v4. j-split x2 partials as before.
__global__ __launch_bounds__(512) void k_attn(
    const float* __restrict__ edge, const float* __restrict__ mask,
    const float* __restrict__ We,
    const f16* __restrict__ qf, const f16* __restrict__ kf,
    const f16* __restrict__ vT, f16* __restrict__ part_o,
    float2* __restrict__ part_md){
  __shared__ f16 pm_s[8][16*40];
  __shared__ u16 biasT[8][2][512];
  int t = threadIdx.x, lane = t & 63, w = t >> 6;   // w = head
  int bid = blockIdx.x;                              // 512 = b(4) x it(64) x s(2)
  int s = bid & 1, it = (bid >> 1) & 63, b = bid >> 7;
  int fr = lane & 15, g = lane >> 4;
  int bh = b*8 + w;
  int c = lane & 3, vq = lane >> 2;

  // per-lane We slice for this head: e rows c*4..c*4+3, column w
  float wc[4];
  #pragma unroll
  for (int k = 0; k < 4; k++) wc[k] = We[(c*4 + k)*8 + w];

  size_t qb = ((size_t)bh * 1024 + it*16 + fr) * 64 + g*8;
  f16x8 qf0 = *(const f16x8*)(qf + qb);
  f16x8 qf1 = *(const f16x8*)(qf + qb + 32);

  const float* mbase = mask + (size_t)(b*1024 + it*16) * 1024;
  const f16*   kbase = kf + (size_t)bh * 65536;
  const f16*   vbase = vT + (size_t)bh * 65536;
  const float* ebase = edge + ((size_t)(b*1024 + it*16) * 1024 + s*512) * 16;

  f32x4 oacc[4];
  #pragma unroll
  for (int vf = 0; vf < 4; vf++) oacc[vf] = (f32x4){0.f,0.f,0.f,0.f};
  float mrun[4], den[4];
  #pragma unroll
  for (int r = 0; r < 4; r++){ mrun[r] = -3e38f; den[r] = 0.f; }

  #pragma unroll 1
  for (int jt = 0; jt < 16; jt++){
    int j0 = s*512 + (jt << 5);
    int pb_ = jt & 1;

    // issue K/V + mask loads first (their latency hides under edge FMA phase)
    const f16* kp = kbase + (size_t)(j0 + fr) * 64 + g*8;
    f16x8 kf00 = *(const f16x8*)(kp);
    f16x8 kf01 = *(const f16x8*)(kp + 32);
    f16x8 kf10 = *(const f16x8*)(kp + 16*64);
    f16x8 kf11 = *(const f16x8*)(kp + 16*64 + 32);
    f16x8 vfr[4];
    #pragma unroll
    for (int vf = 0; vf < 4; vf++)
      vfr[vf] = *(const f16x8*)(vbase + (size_t)(vf*16 + fr) * 1024 + j0 + g*8);
    float ms0[4], ms1[4];
    #pragma unroll
    for (int r = 0; r < 4; r++){
      int row = g*4 + r;
      ms0[r] = mbase[(size_t)row*1024 + j0 + fr];
      ms1[r] = mbase[(size_t)row*1024 + j0 + 16 + fr];
    }

    // (A) edge tile -> this head's bias, quad-cooperative, coalesced 1KB loads
    const float* etile = ebase + (size_t)jt * 512;   // jt*32 cols * 16 e
    #pragma unroll 1
    for (int n4 = 0; n4 < 8; n4++){
      float4 e[4];
      #pragma unroll
      for (int m = 0; m < 4; m++){
        int n = n4*4 + m;                            // 32 chunks of 1KB
        e[m] = *(const float4*)(etile + (size_t)(n >> 1)*16384 + (n & 1)*256 + lane*4);
      }
      #pragma unroll
      for (int m = 0; m < 4; m++){
        int n = n4*4 + m;
        float pbv = e[m].x*wc[0] + e[m].y*wc[1] + e[m].z*wc[2] + e[m].w*wc[3];
        pbv += __shfl_xor(pbv, 1, 64);
        pbv += __shfl_xor(pbv, 2, 64);
        int v = n*16 + vq;
        int il = v >> 5, jl = v & 31;
        int p = ((il >> 2)*16 + (jl & 15))*8 + (jl >> 4)*4 + (il & 3);
        if (c == 0) biasT[w][pb_][p] = __builtin_bit_cast(u16, (f16)pbv);
      }
    }
    asm volatile("s_waitcnt lgkmcnt(0)" ::: "memory");
    __builtin_amdgcn_sched_barrier(0);

    // (B) bias in fragment order from wave-private LDS
    float bs0[4], bs1[4];
    #pragma unroll
    for (int r = 0; r < 4; r++){
      bs0[r] = (float)__builtin_bit_cast(f16, biasT[w][pb_][(g*16 + fr)*8 + r]);
      bs1[r] = (float)__builtin_bit_cast(f16, biasT[w][pb_][(g*16 + fr)*8 + 4 + r]);
    }
    __builtin_amdgcn_sched_barrier(0);

    // (C) QK^T + bias + online softmax (identical to v4)
    f32x4 lg0 = (f32x4){0.f,0.f,0.f,0.f};
    f32x4 lg1 = (f32x4){0.f,0.f,0.f,0.f};
    lg0 = MFMAH(qf0, kf00, lg0); lg1 = MFMAH(qf0, kf10, lg1);
    lg0 = MFMAH(qf1, kf01, lg0); lg1 = MFMAH(qf1, kf11, lg1);

    float tm[4];
    #pragma unroll
    for (int r = 0; r < 4; r++){
      lg0[r] += bs0[r];
      lg1[r] += bs1[r];
      tm[r] = fmaxf(lg0[r], lg1[r]);
    }
    #pragma unroll
    for (int mk = 1; mk < 16; mk <<= 1){
      #pragma unroll
      for (int r = 0; r < 4; r++) tm[r] = fmaxf(tm[r], __shfl_xor(tm[r], mk, 16));
    }
    float p0[4], p1[4], scl[4], ps[4];
    #pragma unroll
    for (int r = 0; r < 4; r++){
      float nm = fmaxf(mrun[r], tm[r]);
      scl[r] = exp2f((mrun[r] - nm) * 1.44269504089f);
      mrun[r] = nm;
      p0[r] = exp2f((lg0[r] - nm) * 1.44269504089f);
      p1[r] = exp2f((lg1[r] - nm) * 1.44269504089f);
      ps[r] = p0[r] + p1[r];
    }
    #pragma unroll
    for (int mk = 1; mk < 16; mk <<= 1){
      #pragma unroll
      for (int r = 0; r < 4; r++) ps[r] += __shfl_xor(ps[r], mk, 16);
    }
    #pragma unroll
    for (int r = 0; r < 4; r++) den[r] = den[r] * scl[r] + ps[r];
    #pragma unroll
    for (int vf = 0; vf < 4; vf++)
      #pragma unroll
      for (int r = 0; r < 4; r++) oacc[vf][r] *= scl[r];

    // (D) masked P -> f16 -> wave-private LDS scatter, A-frag read, PV
    #pragma unroll
    for (int r = 0; r < 4; r++){
      int row = g*4 + r;
      pm_s[w][row*40 + fr]      = (f16)(p0[r] * ms0[r]);
      pm_s[w][row*40 + 16 + fr] = (f16)(p1[r] * ms1[r]);
    }
    asm volatile("s_waitcnt lgkmcnt(0)" ::: "memory");
    __builtin_amdgcn_sched_barrier(0);
    f16x8 pa = *(const f16x8*)&pm_s[w][fr*40 + g*8];
    #pragma unroll
    for (int vf = 0; vf < 4; vf++)
      oacc[vf] = MFMAH(pa, vfr[vf], oacc[vf]);
  }

  // partial store: o/den f16, (m, den) fp32
  float id[4];
  #pragma unroll
  for (int r = 0; r < 4; r++) id[r] = 1.0f / den[r];
  #pragma unroll
  for (int vf = 0; vf < 4; vf++)
    #pragma unroll
    for (int r = 0; r < 4; r++){
      int row = g*4 + r;
      part_o[((size_t)((s*32 + bh) * 1024) + it*16 + row) * 64 + vf*16 + fr] =
          (f16)(oacc[vf][r] * id[r]);
    }
  if (fr == 0){
    #pragma unroll
    for (int r = 0; r < 4; r++){
      int row = g*4 + r;
      part_md[(size_t)(s*32 + bh) * 1024 + it*16 + row] = make_float2(mrun[r], den[r]);
    }
  }
}

// ---------------------------------------------------------------------------
// K4: combine the 2 j-split partials -> AO f16 [b,i][h*64+d].
__global__ __launch_bounds__(256) void k_combine(
    const f16* __restrict__ part_o, const float2* __restrict__ part_md,
    f16* __restrict__ AO){
  int wg   = blockIdx.x * 4 + (threadIdx.x >> 6);   // row id 0..32767
  int lane = threadIdx.x & 63;
  int bh = wg >> 10, i = wg & 1023;
  int b = bh >> 3, h = bh & 7;
  float2 md[2];
  float M = -3e38f;
  #pragma unroll
  for (int s = 0; s < 2; s++){
    md[s] = part_md[(size_t)(s*32 + bh) * 1024 + i];
    M = fmaxf(M, md[s].x);
  }
  float wsum = 0.f, o = 0.f;
  #pragma unroll
  for (int s = 0; s < 2; s++){
    float wq = md[s].y * exp2f((md[s].x - M) * 1.44269504089f);
    wsum += wq;
    o += wq * (float)part_o[((size_t)((s*32 + bh) * 1024) + i) * 64 + lane];
  }
  AO[((size_t)(b*1024 + i)) * 512 + h*64 + lane] = (f16)(o * 0.125f / wsum);
}

// ---------------------------------------------------------------------------
// K5: out = AO @ Wo + residual. f16 single-pass, 64x128 tile, BK=32.
__global__ __launch_bounds__(256) void k_out(
    const f16* __restrict__ AO, const f16* __restrict__ WoT,
    const float* __restrict__ x, float* __restrict__ out){
  __shared__ f16 As[64*32], Bs[128*32];
  int bid = blockIdx.x;
  int mt = bid & 63, nt = bid >> 6;
  int m0 = mt << 6, n0 = nt << 7;
  int t = threadIdx.x, lane = t & 63, w = t >> 6;
  int wm = (w >> 1) << 5, wn = (w & 1) << 6;
  int fr = lane & 15, g = lane >> 4;
  f32x4 acc[2][4];
  #pragma unroll
  for (int i = 0; i < 2; i++)
    #pragma unroll
    for (int j = 0; j < 4; j++) acc[i][j] = (f32x4){0.f,0.f,0.f,0.f};

  for (int k0 = 0; k0 < 512; k0 += 32){
    {
      int row = t >> 2, part = t & 3;
      gld16(AO + (size_t)(m0+row)*512 + k0 + part*8, &As[w*512]);
    }
    #pragma unroll
    for (int q = 0; q < 2; q++){
      int c = ((q << 2) + w) * 64 + lane;
      int row = c >> 2, part = c & 3;
      gld16(WoT + (size_t)(n0+row)*512 + k0 + part*8, &Bs[((q<<2)+w)*512]);
    }
    __syncthreads();
    f16x8 af[2], bf_[4];
    #pragma unroll
    for (int mi = 0; mi < 2; mi++) af[mi]  = *(const f16x8*)&As[(wm + mi*16 + fr)*32 + g*8];
    #pragma unroll
    for (int ni = 0; ni < 4; ni++) bf_[ni] = *(const f16x8*)&Bs[(wn + ni*16 + fr)*32 + g*8];
    #pragma unroll
    for (int mi = 0; mi < 2; mi++)
      #pragma unroll
      for (int ni = 0; ni < 4; ni++)
        acc[mi][ni] = MFMAH(af[mi], bf_[ni], acc[mi][ni]);
    __syncthreads();
  }
  #pragma unroll
  for (int mi = 0; mi < 2; mi++)
    #pragma unroll
    for (int ni = 0; ni < 4; ni++)
      #pragma unroll
      for (int r = 0; r < 4; r++){
        size_t gm = m0 + wm + mi*16 + g*4 + r;
        size_t gn = n0 + wn + ni*16 + fr;
        out[gm*512 + gn] = acc[mi][ni][r] + x[gm*512 + gn];
      }
}

// ---------------------------------------------------------------------------
extern "C" void kernel_launch(void* const* d_in, const int* in_sizes, int n_in,
                              void* d_out, int out_size, void* d_ws, size_t ws_size,
                              hipStream_t stream){
  const float* xin   = (const float*)d_in[0];
  const float* edge  = (const float*)d_in[1];
  const float* mask  = (const float*)d_in[2];
  const float* gamma = (const float*)d_in[3];
  const float* beta  = (const float*)d_in[4];
  const float* Wq    = (const float*)d_in[5];
  const float* Wk    = (const float*)d_in[6];
  const float* Wv    = (const float*)d_in[7];
  const float* We    = (const float*)d_in[8];
  const float* Wo    = (const float*)d_in[9];
  float* out = (float*)d_out;

  f16* p   = (f16*)d_ws;
  f16* WT      = p;   p += 1536*512;        // dead after k_qkv
  f16* WoT     = p;   p += 512*512;         // live until k_out
  f16* rf      = p;   p += 4096*512;        // dead after k_qkv; AO aliases it
  f16* qf      = p;   p += 2097152;
  f16* kf      = p;   p += 2097152;
  f16* vT      = p;   p += 2097152;
  f16* part_o  = p;   p += 4194304;         // 2 x 32 x 1024 x 64
  float2* part_md = (float2*)p;             // 65536 float2
  f16* AO      = rf;                        // alias (rf dead after k_qkv)

  k_wsplit <<<1024, 256, 0, stream>>>(Wq, Wk, Wv, Wo, WT, WoT);
  k_ln     <<<1024, 256, 0, stream>>>(xin, gamma, beta, rf);
  k_qkv    <<<384,  256, 0, stream>>>(rf, WT, qf, kf, vT);
  k_attn   <<<512,  512, 0, stream>>>(edge, mask, We, qf, kf, vT, part_o, part_md);
  k_combine<<<8192, 256, 0, stream>>>(part_o, part_md, AO);
  k_out    <<<256,  256, 0, stream>>>(AO, WoT, xin, out);
}

// Round 15
// 195.190 us; speedup vs baseline: 1.2664x; 1.2664x over previous
//
#include <hip/hip_runtime.h>

// Problem constants
#define BB 4
#define NN 1024
#define FF 512
#define HH 8
#define DD 64
#define EE 16

typedef unsigned short u16;
typedef _Float16 f16;
typedef __attribute__((ext_vector_type(8))) _Float16 f16x8;
typedef __attribute__((ext_vector_type(4))) _Float16 f16x4;
typedef __attribute__((ext_vector_type(4))) float     f32x4;

#define MFMAH(a,b,c) __builtin_amdgcn_mfma_f32_16x16x32_f16((a),(b),(c),0,0,0)

static __device__ __forceinline__ void gld16(const void* g, void* l){
  __builtin_amdgcn_global_load_lds((const __attribute__((address_space(1))) unsigned int*)g,
                                   (__attribute__((address_space(3))) unsigned int*)l, 16, 0, 0);
}

// ---------------------------------------------------------------------------
// K0: transpose weights -> f16. [Wq|Wk|Wv] (512f x 1536c) -> WT [c][f];
// Wo -> WoT [c][f].
__global__ __launch_bounds__(256) void k_wsplit(
    const float* __restrict__ Wq, const float* __restrict__ Wk,
    const float* __restrict__ Wv, const float* __restrict__ Wo,
    f16* __restrict__ WT, f16* __restrict__ WoT){
  __shared__ float tile[32][33];
  int bid = blockIdx.x, t = threadIdx.x;
  int isA = bid < 768;
  int tb  = isA ? bid : bid - 768;
  int nct = isA ? 48 : 16;
  int ct = tb % nct, ft = tb / nct;
  int c0 = ct * 32, f0 = ft * 32;
  #pragma unroll
  for (int r4 = 0; r4 < 4; r4++){
    int fl = (t >> 5) * 4 + r4, cl = t & 31;
    int f = f0 + fl, c = c0 + cl;
    float v;
    if (isA){
      const float* W = (c < 512) ? Wq : ((c < 1024) ? Wk : Wv);
      v = W[f * 512 + (c & 511)];
    } else {
      v = Wo[f * 512 + c];
    }
    tile[fl][cl] = v;
  }
  __syncthreads();
  #pragma unroll
  for (int r4 = 0; r4 < 4; r4++){
    int cl = (t >> 5) * 4 + r4, fl = t & 31;
    float v = tile[fl][cl];
    int c = c0 + cl, f = f0 + fl;
    if (isA) WT[c * 512 + f]  = (f16)v;
    else     WoT[c * 512 + f] = (f16)v;
  }
}

// ---------------------------------------------------------------------------
// K1: LayerNorm (fp32) -> r as f16. One wave per row.
__global__ __launch_bounds__(256) void k_ln(
    const float* __restrict__ x, const float* __restrict__ gamma,
    const float* __restrict__ beta, f16* __restrict__ rf){
  int row  = blockIdx.x * 4 + (threadIdx.x >> 6);
  int lane = threadIdx.x & 63;
  const float* px = x + (size_t)row * 512 + lane * 8;
  float4 a = *(const float4*)px;
  float4 b = *(const float4*)(px + 4);
  float v[8] = {a.x,a.y,a.z,a.w,b.x,b.y,b.z,b.w};
  float s = 0.f, q = 0.f;
  #pragma unroll
  for (int j = 0; j < 8; j++){ s += v[j]; q += v[j]*v[j]; }
  #pragma unroll
  for (int m = 1; m < 64; m <<= 1){ s += __shfl_xor(s, m, 64); q += __shfl_xor(q, m, 64); }
  float mean = s * (1.f/512.f);
  float var  = q * (1.f/512.f) - mean * mean;
  float rstd = rsqrtf(var + 1e-5f);
  float4 ga = *(const float4*)(gamma + lane*8);
  float4 gb = *(const float4*)(gamma + lane*8 + 4);
  float4 b0 = *(const float4*)(beta  + lane*8);
  float4 b1 = *(const float4*)(beta  + lane*8 + 4);
  float gs[8] = {ga.x,ga.y,ga.z,ga.w,gb.x,gb.y,gb.z,gb.w};
  float bs[8] = {b0.x,b0.y,b0.z,b0.w,b1.x,b1.y,b1.z,b1.w};
  f16x8 hv;
  #pragma unroll
  for (int j = 0; j < 8; j++){
    float r = (v[j] - mean) * rstd * gs[j] + bs[j];
    hv[j] = (f16)r;
  }
  *(f16x8*)(rf + (size_t)row * 512 + lane * 8) = hv;
}

// ---------------------------------------------------------------------------
// K2: QKV projection GEMM, f16 single-pass, 128x128 tile BK=32.
__global__ __launch_bounds__(256) void k_qkv(
    const f16* __restrict__ rf, const f16* __restrict__ WT,
    f16* __restrict__ qf, f16* __restrict__ kf, f16* __restrict__ vT){
  __shared__ f16 As[128*32], Bs[128*32];
  int bid = blockIdx.x;
  int mt = bid & 31, nt = bid >> 5;
  int m0 = mt << 7,  n0 = nt << 7;
  int t = threadIdx.x, lane = t & 63, w = t >> 6;
  int wm = (w >> 1) << 6, wn = (w & 1) << 6;
  int fr = lane & 15, g = lane >> 4;
  f32x4 acc[4][4];
  #pragma unroll
  for (int i = 0; i < 4; i++)
    #pragma unroll
    for (int j = 0; j < 4; j++) acc[i][j] = (f32x4){0.f,0.f,0.f,0.f};

  for (int k0 = 0; k0 < 512; k0 += 32){
    #pragma unroll
    for (int q = 0; q < 2; q++){
      int c = ((q << 2) + w) * 64 + lane;
      int row = c >> 2, part = c & 3;
      int ldso = ((q << 2) + w) * 512;
      gld16(rf + (size_t)(m0+row)*512 + k0 + part*8, &As[ldso]);
      gld16(WT + (size_t)(n0+row)*512 + k0 + part*8, &Bs[ldso]);
    }
    __syncthreads();
    f16x8 a[4], b[4];
    #pragma unroll
    for (int mi = 0; mi < 4; mi++) a[mi] = *(const f16x8*)&As[(wm + mi*16 + fr)*32 + g*8];
    #pragma unroll
    for (int ni = 0; ni < 4; ni++) b[ni] = *(const f16x8*)&Bs[(wn + ni*16 + fr)*32 + g*8];
    #pragma unroll
    for (int mi = 0; mi < 4; mi++)
      #pragma unroll
      for (int ni = 0; ni < 4; ni++)
        acc[mi][ni] = MFMAH(a[mi], b[ni], acc[mi][ni]);
    __syncthreads();
  }
  #pragma unroll
  for (int mi = 0; mi < 4; mi++)
    #pragma unroll
    for (int ni = 0; ni < 4; ni++)
      #pragma unroll
      for (int r = 0; r < 4; r++){
        int gm = m0 + wm + mi*16 + g*4 + r;
        int gc = n0 + wn + ni*16 + fr;
        float vv = acc[mi][ni][r];
        int b = gm >> 10, i = gm & 1023;
        int mat = gc >> 9, h = (gc >> 6) & 7, d = gc & 63;
        size_t idx = ((size_t)((b << 3) + h) * 1024 + i) * 64 + d;
        if      (mat == 0) qf[idx] = (f16)vv;
        else if (mat == 1) kf[idx] = (f16)vv;
        else vT[((size_t)((b << 3) + h) * 64 + d) * 1024 + i] = (f16)vv;
      }
}

// ---------------------------------------------------------------------------
// K_bias v8 (round-13 best): 2-deep ping-pong register prefetch, quad-coop
// FMA + quad shfl, per-wave LDS transpose tile, coalesced f16x8 stores.
// biasP[bh][i][j] f16.
__global__ __launch_bounds__(256) void k_bias(
    const float* __restrict__ edge, const float* __restrict__ We,
    f16* __restrict__ biasP){
  __shared__ char outb[4][1280];           // per-wave 64 rows x 20B
  int t = threadIdx.x, lane = t & 63, w = t >> 6;
  int c = lane & 3, vq = lane >> 2;
  float wr[4][8];
  #pragma unroll
  for (int r = 0; r < 4; r++){
    float4 wa = *(const float4*)(We + (c*4 + r)*8);
    float4 wb = *(const float4*)(We + (c*4 + r)*8 + 4);
    wr[r][0]=wa.x; wr[r][1]=wa.y; wr[r][2]=wa.z; wr[r][3]=wa.w;
    wr[r][4]=wb.x; wr[r][5]=wb.y; wr[r][6]=wb.z; wr[r][7]=wb.w;
  }
  int bid = blockIdx.x;                    // 4096 = b(4) x i(1024)
  int i = bid & 1023, b = bid >> 10;
  const float* erow = edge + (size_t)bid * 16384;
  int h = lane >> 3, vb = lane & 7;
  f16* obase = biasP + (size_t)(b*8 + h) * 1048576 + (size_t)i * 1024;

  auto process = [&](const float4* e, int bt){
    #pragma unroll
    for (int n = 0; n < 4; n++){
      float p[8];
      #pragma unroll
      for (int hh = 0; hh < 8; hh++)
        p[hh] = e[n].x*wr[0][hh] + e[n].y*wr[1][hh] + e[n].z*wr[2][hh] + e[n].w*wr[3][hh];
      #pragma unroll
      for (int hh = 0; hh < 8; hh++){
        p[hh] += __shfl_xor(p[hh], 1, 64);
        p[hh] += __shfl_xor(p[hh], 2, 64);
      }
      unsigned lo = (unsigned)__builtin_bit_cast(u16, (f16)p[2*c]);
      unsigned hi = (unsigned)__builtin_bit_cast(u16, (f16)p[2*c + 1]);
      *(unsigned*)(&outb[w][(n*16 + vq)*20 + c*4]) = lo | (hi << 16);
    }
    asm volatile("s_waitcnt lgkmcnt(0)" ::: "memory");
    __builtin_amdgcn_sched_barrier(0);
    f16x8 ov;
    #pragma unroll
    for (int q = 0; q < 8; q++)
      ov[q] = __builtin_bit_cast(f16, *(const u16*)(&outb[w][(vb*8 + q)*20 + h*2]));
    *(f16x8*)(obase + (w*16 + bt*4)*16 + vb*8) = ov;
    asm volatile("s_waitcnt lgkmcnt(0)" ::: "memory");
    __builtin_amdgcn_sched_barrier(0);
  };

  float4 eA[4], eB[4];
  #pragma unroll
  for (int n = 0; n < 4; n++)
    eA[n] = *(const float4*)(erow + (size_t)(w*16 + n)*256 + lane*4);
  #pragma unroll
  for (int n = 0; n < 4; n++)
    eB[n] = *(const float4*)(erow + (size_t)(w*16 + 4 + n)*256 + lane*4);
  process(eA, 0);
  #pragma unroll
  for (int n = 0; n < 4; n++)
    eA[n] = *(const float4*)(erow + (size_t)(w*16 + 8 + n)*256 + lane*4);
  process(eB, 1);
  #pragma unroll
  for (int n = 0; n < 4; n++)
    eB[n] = *(const float4*)(erow + (size_t)(w*16 + 12 + n)*256 + lane*4);
  process(eA, 2);
  process(eB, 3);
}

// ---------------------------------------------------------------------------
// K3: fused attention v6 — barrier-free + j-split x4 for occupancy.
// 2048 blocks x 256 thr; block = (b,h,it), its 4 waves cover s=0..3
// (K/V shared via L1). Each wave: 8 jt iters over j in [s*256, s*256+256).
__global__ __launch_bounds__(256) void k_attn(
    const f16* __restrict__ biasP, const float* __restrict__ mask,
    const f16* __restrict__ qf, const f16* __restrict__ kf,
    const f16* __restrict__ vT, f16* __restrict__ part_o,
    float2* __restrict__ part_md){
  __shared__ f16 pm_s[4][16*40];
  int t = threadIdx.x, lane = t & 63, w = t >> 6;
  int wid = blockIdx.x * 4 + w;
  int s = wid & 3, it = (wid >> 2) & 63, h = (wid >> 8) & 7, b = wid >> 11;
  int fr = lane & 15, g = lane >> 4;
  int bh = b*8 + h;

  size_t qb = ((size_t)bh * 1024 + it*16 + fr) * 64 + g*8;
  f16x8 qf0 = *(const f16x8*)(qf + qb);
  f16x8 qf1 = *(const f16x8*)(qf + qb + 32);

  const f16*   bbase = biasP + ((size_t)bh * 1024 + it*16) * 1024;
  const float* mbase = mask + (size_t)(b*1024 + it*16) * 1024;
  const f16*   kbase = kf + (size_t)bh * 65536;
  const f16*   vbase = vT + (size_t)bh * 65536;

  f32x4 oacc[4];
  #pragma unroll
  for (int vf = 0; vf < 4; vf++) oacc[vf] = (f32x4){0.f,0.f,0.f,0.f};
  float mrun[4], den[4];
  #pragma unroll
  for (int r = 0; r < 4; r++){ mrun[r] = -3e38f; den[r] = 0.f; }

  #pragma unroll 1
  for (int jt = s*8; jt < s*8 + 8; jt++){
    int j0 = jt << 5;
    const f16* kp = kbase + (size_t)(j0 + fr) * 64 + g*8;
    f16x8 kf00 = *(const f16x8*)(kp);
    f16x8 kf01 = *(const f16x8*)(kp + 32);
    f16x8 kf10 = *(const f16x8*)(kp + 16*64);
    f16x8 kf11 = *(const f16x8*)(kp + 16*64 + 32);
    f16x8 vfr[4];
    #pragma unroll
    for (int vf = 0; vf < 4; vf++)
      vfr[vf] = *(const f16x8*)(vbase + (size_t)(vf*16 + fr) * 1024 + j0 + g*8);
    float bs0[4], bs1[4], ms0[4], ms1[4];
    #pragma unroll
    for (int r = 0; r < 4; r++){
      int row = g*4 + r;
      bs0[r] = (float)bbase[(size_t)row*1024 + j0 + fr];
      bs1[r] = (float)bbase[(size_t)row*1024 + j0 + 16 + fr];
      ms0[r] = mbase[(size_t)row*1024 + j0 + fr];
      ms1[r] = mbase[(size_t)row*1024 + j0 + 16 + fr];
    }

    f32x4 lg0 = (f32x4){0.f,0.f,0.f,0.f};
    f32x4 lg1 = (f32x4){0.f,0.f,0.f,0.f};
    lg0 = MFMAH(qf0, kf00, lg0); lg1 = MFMAH(qf0, kf10, lg1);
    lg0 = MFMAH(qf1, kf01, lg0); lg1 = MFMAH(qf1, kf11, lg1);

    float tm[4];
    #pragma unroll
    for (int r = 0; r < 4; r++){
      lg0[r] += bs0[r];
      lg1[r] += bs1[r];
      tm[r] = fmaxf(lg0[r], lg1[r]);
    }
    #pragma unroll
    for (int mk = 1; mk < 16; mk <<= 1){
      #pragma unroll
      for (int r = 0; r < 4; r++) tm[r] = fmaxf(tm[r], __shfl_xor(tm[r], mk, 16));
    }
    float p0[4], p1[4], scl[4], ps[4];
    #pragma unroll
    for (int r = 0; r < 4; r++){
      float nm = fmaxf(mrun[r], tm[r]);
      scl[r] = exp2f((mrun[r] - nm) * 1.44269504089f);
      mrun[r] = nm;
      p0[r] = exp2f((lg0[r] - nm) * 1.44269504089f);
      p1[r] = exp2f((lg1[r] - nm) * 1.44269504089f);
      ps[r] = p0[r] + p1[r];
    }
    #pragma unroll
    for (int mk = 1; mk < 16; mk <<= 1){
      #pragma unroll
      for (int r = 0; r < 4; r++) ps[r] += __shfl_xor(ps[r], mk, 16);
    }
    #pragma unroll
    for (int r = 0; r < 4; r++) den[r] = den[r] * scl[r] + ps[r];
    #pragma unroll
    for (int vf = 0; vf < 4; vf++)
      #pragma unroll
      for (int r = 0; r < 4; r++) oacc[vf][r] *= scl[r];

    #pragma unroll
    for (int r = 0; r < 4; r++){
      int row = g*4 + r;
      pm_s[w][row*40 + fr]      = (f16)(p0[r] * ms0[r]);
      pm_s[w][row*40 + 16 + fr] = (f16)(p1[r] * ms1[r]);
    }
    asm volatile("s_waitcnt lgkmcnt(0)" ::: "memory");
    f16x8 pa = *(const f16x8*)&pm_s[w][fr*40 + g*8];
    #pragma unroll
    for (int vf = 0; vf < 4; vf++)
      oacc[vf] = MFMAH(pa, vfr[vf], oacc[vf]);
  }

  float id[4];
  #pragma unroll
  for (int r = 0; r < 4; r++) id[r] = 1.0f / den[r];
  #pragma unroll
  for (int vf = 0; vf < 4; vf++)
    #pragma unroll
    for (int r = 0; r < 4; r++){
      int row = g*4 + r;
      part_o[((size_t)((s*32 + bh) * 1024) + it*16 + row) * 64 + vf*16 + fr] =
          (f16)(oacc[vf][r] * id[r]);
    }
  if (fr == 0){
    #pragma unroll
    for (int r = 0; r < 4; r++){
      int row = g*4 + r;
      part_md[(size_t)(s*32 + bh) * 1024 + it*16 + row] = make_float2(mrun[r], den[r]);
    }
  }
}

// ---------------------------------------------------------------------------
// K4: combine the 4 j-split partials -> AO f16 [b,i][h*64+d].
__global__ __launch_bounds__(256) void k_combine(
    const f16* __restrict__ part_o, const float2* __restrict__ part_md,
    f16* __restrict__ AO){
  int wg   = blockIdx.x * 4 + (threadIdx.x >> 6);   // row id 0..32767
  int lane = threadIdx.x & 63;
  int bh = wg >> 10, i = wg & 1023;
  int b = bh >> 3, h = bh & 7;
  float2 md[4];
  float M = -3e38f;
  #pragma unroll
  for (int s = 0; s < 4; s++){
    md[s] = part_md[(size_t)(s*32 + bh) * 1024 + i];
    M = fmaxf(M, md[s].x);
  }
  float wsum = 0.f, o = 0.f;
  #pragma unroll
  for (int s = 0; s < 4; s++){
    float wq = md[s].y * exp2f((md[s].x - M) * 1.44269504089f);
    wsum += wq;
    o += wq * (float)part_o[((size_t)((s*32 + bh) * 1024) + i) * 64 + lane];
  }
  AO[((size_t)(b*1024 + i)) * 512 + h*64 + lane] = (f16)(o * 0.125f / wsum);
}

// ---------------------------------------------------------------------------
// K5: out = AO @ Wo + residual. f16 single-pass, 64x128 tile, BK=32.
__global__ __launch_bounds__(256) void k_out(
    const f16* __restrict__ AO, const f16* __restrict__ WoT,
    const float* __restrict__ x, float* __restrict__ out){
  __shared__ f16 As[64*32], Bs[128*32];
  int bid = blockIdx.x;
  int mt = bid & 63, nt = bid >> 6;
  int m0 = mt << 6, n0 = nt << 7;
  int t = threadIdx.x, lane = t & 63, w = t >> 6;
  int wm = (w >> 1) << 5, wn = (w & 1) << 6;
  int fr = lane & 15, g = lane >> 4;
  f32x4 acc[2][4];
  #pragma unroll
  for (int i = 0; i < 2; i++)
    #pragma unroll
    for (int j = 0; j < 4; j++) acc[i][j] = (f32x4){0.f,0.f,0.f,0.f};

  for (int k0 = 0; k0 < 512; k0 += 32){
    {
      int row = t >> 2, part = t & 3;
      gld16(AO + (size_t)(m0+row)*512 + k0 + part*8, &As[w*512]);
    }
    #pragma unroll
    for (int q = 0; q < 2; q++){
      int c = ((q << 2) + w) * 64 + lane;
      int row = c >> 2, part = c & 3;
      gld16(WoT + (size_t)(n0+row)*512 + k0 + part*8, &Bs[((q<<2)+w)*512]);
    }
    __syncthreads();
    f16x8 af[2], bf_[4];
    #pragma unroll
    for (int mi = 0; mi < 2; mi++) af[mi]  = *(const f16x8*)&As[(wm + mi*16 + fr)*32 + g*8];
    #pragma unroll
    for (int ni = 0; ni < 4; ni++) bf_[ni] = *(const f16x8*)&Bs[(wn + ni*16 + fr)*32 + g*8];
    #pragma unroll
    for (int mi = 0; mi < 2; mi++)
      #pragma unroll
      for (int ni = 0; ni < 4; ni++)
        acc[mi][ni] = MFMAH(af[mi], bf_[ni], acc[mi][ni]);
    __syncthreads();
  }
  #pragma unroll
  for (int mi = 0; mi < 2; mi++)
    #pragma unroll
    for (int ni = 0; ni < 4; ni++)
      #pragma unroll
      for (int r = 0; r < 4; r++){
        size_t gm = m0 + wm + mi*16 + g*4 + r;
        size_t gn = n0 + wn + ni*16 + fr;
        out[gm*512 + gn] = acc[mi][ni][r] + x[gm*512 + gn];
      }
}

// ---------------------------------------------------------------------------
extern "C" void kernel_launch(void* const* d_in, const int* in_sizes, int n_in,
                              void* d_out, int out_size, void* d_ws, size_t ws_size,
                              hipStream_t stream){
  const float* xin   = (const float*)d_in[0];
  const float* edge  = (const float*)d_in[1];
  const float* mask  = (const float*)d_in[2];
  const float* gamma = (const float*)d_in[3];
  const float* beta  = (const float*)d_in[4];
  const float* Wq    = (const float*)d_in[5];
  const float* Wk    = (const float*)d_in[6];
  const float* Wv    = (const float*)d_in[7];
  const float* We    = (const float*)d_in[8];
  const float* Wo    = (const float*)d_in[9];
  float* out = (float*)d_out;

  f16* p   = (f16*)d_ws;
  f16* WT      = p;   p += 1536*512;        // dead after k_qkv
  f16* WoT     = p;   p += 512*512;         // live until k_out
  f16* rf      = p;   p += 4096*512;        // dead after k_qkv; AO aliases it
  f16* qf      = p;   p += 2097152;
  f16* kf      = p;   p += 2097152;
  f16* vT      = p;   p += 2097152;
  f16* biasP   = p;   p += 33554432;        // [bh][i][j] f16, 64 MB
  f16* part_o  = p;   p += 8388608;         // 4 x 32 x 1024 x 64
  float2* part_md = (float2*)p;             // 131072 float2
  f16* AO      = rf;                        // alias (rf dead after k_qkv)

  k_wsplit <<<1024, 256, 0, stream>>>(Wq, Wk, Wv, Wo, WT, WoT);
  k_ln     <<<1024, 256, 0, stream>>>(xin, gamma, beta, rf);
  k_qkv    <<<384,  256, 0, stream>>>(rf, WT, qf, kf, vT);
  k_bias   <<<4096, 256, 0, stream>>>(edge, We, biasP);
  k_attn   <<<2048, 256, 0, stream>>>(biasP, mask, qf, kf, vT, part_o, part_md);
  k_combine<<<8192, 256, 0, stream>>>(part_o, part_md, AO);
  k_out    <<<256,  256, 0, stream>>>(AO, WoT, xin, out);
}

// Round 16
// 172.900 us; speedup vs baseline: 1.4297x; 1.1289x over previous
//
#include <hip/hip_runtime.h>

// Problem constants
#define BB 4
#define NN 1024
#define FF 512
#define HH 8
#define DD 64
#define EE 16

typedef unsigned short u16;
typedef _Float16 f16;
typedef __attribute__((ext_vector_type(8))) _Float16 f16x8;
typedef __attribute__((ext_vector_type(4))) _Float16 f16x4;
typedef __attribute__((ext_vector_type(4))) float     f32x4;

#define MFMAH(a,b,c) __builtin_amdgcn_mfma_f32_16x16x32_f16((a),(b),(c),0,0,0)

static __device__ __forceinline__ void gld16(const void* g, void* l){
  __builtin_amdgcn_global_load_lds((const __attribute__((address_space(1))) unsigned int*)g,
                                   (__attribute__((address_space(3))) unsigned int*)l, 16, 0, 0);
}

// ---------------------------------------------------------------------------
// K_prep: merged weight-transpose (bid<1024) + LayerNorm (bid>=1024).
__global__ __launch_bounds__(256) void k_prep(
    const float* __restrict__ Wq, const float* __restrict__ Wk,
    const float* __restrict__ Wv, const float* __restrict__ Wo,
    const float* __restrict__ x, const float* __restrict__ gamma,
    const float* __restrict__ beta,
    f16* __restrict__ WT, f16* __restrict__ WoT, f16* __restrict__ rf){
  __shared__ float tile[32][33];
  int bid = blockIdx.x, t = threadIdx.x;
  if (bid < 1024){
    // ---- weight transpose ----
    int isA = bid < 768;
    int tb  = isA ? bid : bid - 768;
    int nct = isA ? 48 : 16;
    int ct = tb % nct, ft = tb / nct;
    int c0 = ct * 32, f0 = ft * 32;
    #pragma unroll
    for (int r4 = 0; r4 < 4; r4++){
      int fl = (t >> 5) * 4 + r4, cl = t & 31;
      int f = f0 + fl, c = c0 + cl;
      float v;
      if (isA){
        const float* W = (c < 512) ? Wq : ((c < 1024) ? Wk : Wv);
        v = W[f * 512 + (c & 511)];
      } else {
        v = Wo[f * 512 + c];
      }
      tile[fl][cl] = v;
    }
    __syncthreads();
    #pragma unroll
    for (int r4 = 0; r4 < 4; r4++){
      int cl = (t >> 5) * 4 + r4, fl = t & 31;
      float v = tile[fl][cl];
      int c = c0 + cl, f = f0 + fl;
      if (isA) WT[c * 512 + f]  = (f16)v;
      else     WoT[c * 512 + f] = (f16)v;
    }
  } else {
    // ---- LayerNorm ----
    int row  = (bid - 1024) * 4 + (t >> 6);
    int lane = t & 63;
    const float* px = x + (size_t)row * 512 + lane * 8;
    float4 a = *(const float4*)px;
    float4 b = *(const float4*)(px + 4);
    float v[8] = {a.x,a.y,a.z,a.w,b.x,b.y,b.z,b.w};
    float s = 0.f, q = 0.f;
    #pragma unroll
    for (int j = 0; j < 8; j++){ s += v[j]; q += v[j]*v[j]; }
    #pragma unroll
    for (int m = 1; m < 64; m <<= 1){ s += __shfl_xor(s, m, 64); q += __shfl_xor(q, m, 64); }
    float mean = s * (1.f/512.f);
    float var  = q * (1.f/512.f) - mean * mean;
    float rstd = rsqrtf(var + 1e-5f);
    float4 ga = *(const float4*)(gamma + lane*8);
    float4 gb = *(const float4*)(gamma + lane*8 + 4);
    float4 b0 = *(const float4*)(beta  + lane*8);
    float4 b1 = *(const float4*)(beta  + lane*8 + 4);
    float gs[8] = {ga.x,ga.y,ga.z,ga.w,gb.x,gb.y,gb.z,gb.w};
    float bs[8] = {b0.x,b0.y,b0.z,b0.w,b1.x,b1.y,b1.z,b1.w};
    f16x8 hv;
    #pragma unroll
    for (int j = 0; j < 8; j++){
      float r = (v[j] - mean) * rstd * gs[j] + bs[j];
      hv[j] = (f16)r;
    }
    *(f16x8*)(rf + (size_t)row * 512 + lane * 8) = hv;
  }
}

// ---------------------------------------------------------------------------
// K_bq: merged QKV GEMM (bid<384, scheduled first -> overlaps) + bias stream
// (bid>=384). QKV body = proven f16 128x128 BK=32; bias body = proven v8.
__global__ __launch_bounds__(256) void k_bq(
    const f16* __restrict__ rf, const f16* __restrict__ WT,
    f16* __restrict__ qf, f16* __restrict__ kf, f16* __restrict__ vT,
    const float* __restrict__ edge, const float* __restrict__ We,
    f16* __restrict__ biasP){
  __shared__ f16 As[128*32], Bs[128*32];     // qkv
  __shared__ char outb[4][1280];             // bias
  int t = threadIdx.x, lane = t & 63, w = t >> 6;

  if (blockIdx.x < 384){
    // ---------------- QKV GEMM ----------------
    int bid = blockIdx.x;
    int mt = bid & 31, nt = bid >> 5;
    int m0 = mt << 7,  n0 = nt << 7;
    int wm = (w >> 1) << 6, wn = (w & 1) << 6;
    int fr = lane & 15, g = lane >> 4;
    f32x4 acc[4][4];
    #pragma unroll
    for (int i = 0; i < 4; i++)
      #pragma unroll
      for (int j = 0; j < 4; j++) acc[i][j] = (f32x4){0.f,0.f,0.f,0.f};

    for (int k0 = 0; k0 < 512; k0 += 32){
      #pragma unroll
      for (int q = 0; q < 2; q++){
        int c = ((q << 2) + w) * 64 + lane;
        int row = c >> 2, part = c & 3;
        int ldso = ((q << 2) + w) * 512;
        gld16(rf + (size_t)(m0+row)*512 + k0 + part*8, &As[ldso]);
        gld16(WT + (size_t)(n0+row)*512 + k0 + part*8, &Bs[ldso]);
      }
      __syncthreads();
      f16x8 a[4], b[4];
      #pragma unroll
      for (int mi = 0; mi < 4; mi++) a[mi] = *(const f16x8*)&As[(wm + mi*16 + fr)*32 + g*8];
      #pragma unroll
      for (int ni = 0; ni < 4; ni++) b[ni] = *(const f16x8*)&Bs[(wn + ni*16 + fr)*32 + g*8];
      #pragma unroll
      for (int mi = 0; mi < 4; mi++)
        #pragma unroll
        for (int ni = 0; ni < 4; ni++)
          acc[mi][ni] = MFMAH(a[mi], b[ni], acc[mi][ni]);
      __syncthreads();
    }
    #pragma unroll
    for (int mi = 0; mi < 4; mi++)
      #pragma unroll
      for (int ni = 0; ni < 4; ni++)
        #pragma unroll
        for (int r = 0; r < 4; r++){
          int gm = m0 + wm + mi*16 + g*4 + r;
          int gc = n0 + wn + ni*16 + fr;
          float vv = acc[mi][ni][r];
          int b = gm >> 10, i = gm & 1023;
          int mat = gc >> 9, h = (gc >> 6) & 7, d = gc & 63;
          size_t idx = ((size_t)((b << 3) + h) * 1024 + i) * 64 + d;
          if      (mat == 0) qf[idx] = (f16)vv;
          else if (mat == 1) kf[idx] = (f16)vv;
          else vT[((size_t)((b << 3) + h) * 64 + d) * 1024 + i] = (f16)vv;
        }
  } else {
    // ---------------- bias stream (v8) ----------------
    int bid = blockIdx.x - 384;              // 4096 = b(4) x i(1024)
    int c = lane & 3, vq = lane >> 2;
    float wr[4][8];
    #pragma unroll
    for (int r = 0; r < 4; r++){
      float4 wa = *(const float4*)(We + (c*4 + r)*8);
      float4 wb = *(const float4*)(We + (c*4 + r)*8 + 4);
      wr[r][0]=wa.x; wr[r][1]=wa.y; wr[r][2]=wa.z; wr[r][3]=wa.w;
      wr[r][4]=wb.x; wr[r][5]=wb.y; wr[r][6]=wb.z; wr[r][7]=wb.w;
    }
    int i = bid & 1023, b = bid >> 10;
    const float* erow = edge + (size_t)bid * 16384;
    int h = lane >> 3, vb = lane & 7;
    f16* obase = biasP + (size_t)(b*8 + h) * 1048576 + (size_t)i * 1024;

    auto process = [&](const float4* e, int bt){
      #pragma unroll
      for (int n = 0; n < 4; n++){
        float p[8];
        #pragma unroll
        for (int hh = 0; hh < 8; hh++)
          p[hh] = e[n].x*wr[0][hh] + e[n].y*wr[1][hh] + e[n].z*wr[2][hh] + e[n].w*wr[3][hh];
        #pragma unroll
        for (int hh = 0; hh < 8; hh++){
          p[hh] += __shfl_xor(p[hh], 1, 64);
          p[hh] += __shfl_xor(p[hh], 2, 64);
        }
        unsigned lo = (unsigned)__builtin_bit_cast(u16, (f16)p[2*c]);
        unsigned hi = (unsigned)__builtin_bit_cast(u16, (f16)p[2*c + 1]);
        *(unsigned*)(&outb[w][(n*16 + vq)*20 + c*4]) = lo | (hi << 16);
      }
      asm volatile("s_waitcnt lgkmcnt(0)" ::: "memory");
      __builtin_amdgcn_sched_barrier(0);
      f16x8 ov;
      #pragma unroll
      for (int q = 0; q < 8; q++)
        ov[q] = __builtin_bit_cast(f16, *(const u16*)(&outb[w][(vb*8 + q)*20 + h*2]));
      *(f16x8*)(obase + (w*16 + bt*4)*16 + vb*8) = ov;
      asm volatile("s_waitcnt lgkmcnt(0)" ::: "memory");
      __builtin_amdgcn_sched_barrier(0);
    };

    float4 eA[4], eB[4];
    #pragma unroll
    for (int n = 0; n < 4; n++)
      eA[n] = *(const float4*)(erow + (size_t)(w*16 + n)*256 + lane*4);
    #pragma unroll
    for (int n = 0; n < 4; n++)
      eB[n] = *(const float4*)(erow + (size_t)(w*16 + 4 + n)*256 + lane*4);
    process(eA, 0);
    #pragma unroll
    for (int n = 0; n < 4; n++)
      eA[n] = *(const float4*)(erow + (size_t)(w*16 + 8 + n)*256 + lane*4);
    process(eB, 1);
    #pragma unroll
    for (int n = 0; n < 4; n++)
      eB[n] = *(const float4*)(erow + (size_t)(w*16 + 12 + n)*256 + lane*4);
    process(eA, 2);
    process(eB, 3);
  }
}

// ---------------------------------------------------------------------------
// K3: fused attention (round-13 proven): barrier-free + j-split x2.
// 1024 blocks x 256 thr; wave wid -> s, it, h, b.
__global__ __launch_bounds__(256) void k_attn(
    const f16* __restrict__ biasP, const float* __restrict__ mask,
    const f16* __restrict__ qf, const f16* __restrict__ kf,
    const f16* __restrict__ vT, f16* __restrict__ part_o,
    float2* __restrict__ part_md){
  __shared__ f16 pm_s[4][16*40];
  int t = threadIdx.x, lane = t & 63, w = t >> 6;
  int wid = blockIdx.x * 4 + w;
  int s = wid & 1, it = (wid >> 1) & 63, h = (wid >> 7) & 7, b = wid >> 10;
  int fr = lane & 15, g = lane >> 4;
  int bh = b*8 + h;

  size_t qb = ((size_t)bh * 1024 + it*16 + fr) * 64 + g*8;
  f16x8 qf0 = *(const f16x8*)(qf + qb);
  f16x8 qf1 = *(const f16x8*)(qf + qb + 32);

  const f16*   bbase = biasP + ((size_t)bh * 1024 + it*16) * 1024;
  const float* mbase = mask + (size_t)(b*1024 + it*16) * 1024;
  const f16*   kbase = kf + (size_t)bh * 65536;
  const f16*   vbase = vT + (size_t)bh * 65536;

  f32x4 oacc[4];
  #pragma unroll
  for (int vf = 0; vf < 4; vf++) oacc[vf] = (f32x4){0.f,0.f,0.f,0.f};
  float mrun[4], den[4];
  #pragma unroll
  for (int r = 0; r < 4; r++){ mrun[r] = -3e38f; den[r] = 0.f; }

  #pragma unroll 1
  for (int jt = s*16; jt < s*16 + 16; jt++){
    int j0 = jt << 5;
    const f16* kp = kbase + (size_t)(j0 + fr) * 64 + g*8;
    f16x8 kf00 = *(const f16x8*)(kp);
    f16x8 kf01 = *(const f16x8*)(kp + 32);
    f16x8 kf10 = *(const f16x8*)(kp + 16*64);
    f16x8 kf11 = *(const f16x8*)(kp + 16*64 + 32);
    f16x8 vfr[4];
    #pragma unroll
    for (int vf = 0; vf < 4; vf++)
      vfr[vf] = *(const f16x8*)(vbase + (size_t)(vf*16 + fr) * 1024 + j0 + g*8);
    float bs0[4], bs1[4], ms0[4], ms1[4];
    #pragma unroll
    for (int r = 0; r < 4; r++){
      int row = g*4 + r;
      bs0[r] = (float)bbase[(size_t)row*1024 + j0 + fr];
      bs1[r] = (float)bbase[(size_t)row*1024 + j0 + 16 + fr];
      ms0[r] = mbase[(size_t)row*1024 + j0 + fr];
      ms1[r] = mbase[(size_t)row*1024 + j0 + 16 + fr];
    }

    f32x4 lg0 = (f32x4){0.f,0.f,0.f,0.f};
    f32x4 lg1 = (f32x4){0.f,0.f,0.f,0.f};
    lg0 = MFMAH(qf0, kf00, lg0); lg1 = MFMAH(qf0, kf10, lg1);
    lg0 = MFMAH(qf1, kf01, lg0); lg1 = MFMAH(qf1, kf11, lg1);

    float tm[4];
    #pragma unroll
    for (int r = 0; r < 4; r++){
      lg0[r] += bs0[r];
      lg1[r] += bs1[r];
      tm[r] = fmaxf(lg0[r], lg1[r]);
    }
    #pragma unroll
    for (int mk = 1; mk < 16; mk <<= 1){
      #pragma unroll
      for (int r = 0; r < 4; r++) tm[r] = fmaxf(tm[r], __shfl_xor(tm[r], mk, 16));
    }
    float p0[4], p1[4], scl[4], ps[4];
    #pragma unroll
    for (int r = 0; r < 4; r++){
      float nm = fmaxf(mrun[r], tm[r]);
      scl[r] = exp2f((mrun[r] - nm) * 1.44269504089f);
      mrun[r] = nm;
      p0[r] = exp2f((lg0[r] - nm) * 1.44269504089f);
      p1[r] = exp2f((lg1[r] - nm) * 1.44269504089f);
      ps[r] = p0[r] + p1[r];
    }
    #pragma unroll
    for (int mk = 1; mk < 16; mk <<= 1){
      #pragma unroll
      for (int r = 0; r < 4; r++) ps[r] += __shfl_xor(ps[r], mk, 16);
    }
    #pragma unroll
    for (int r = 0; r < 4; r++) den[r] = den[r] * scl[r] + ps[r];
    #pragma unroll
    for (int vf = 0; vf < 4; vf++)
      #pragma unroll
      for (int r = 0; r < 4; r++) oacc[vf][r] *= scl[r];

    #pragma unroll
    for (int r = 0; r < 4; r++){
      int row = g*4 + r;
      pm_s[w][row*40 + fr]      = (f16)(p0[r] * ms0[r]);
      pm_s[w][row*40 + 16 + fr] = (f16)(p1[r] * ms1[r]);
    }
    asm volatile("s_waitcnt lgkmcnt(0)" ::: "memory");
    f16x8 pa = *(const f16x8*)&pm_s[w][fr*40 + g*8];
    #pragma unroll
    for (int vf = 0; vf < 4; vf++)
      oacc[vf] = MFMAH(pa, vfr[vf], oacc[vf]);
  }

  float id[4];
  #pragma unroll
  for (int r = 0; r < 4; r++) id[r] = 1.0f / den[r];
  #pragma unroll
  for (int vf = 0; vf < 4; vf++)
    #pragma unroll
    for (int r = 0; r < 4; r++){
      int row = g*4 + r;
      part_o[((size_t)((s*32 + bh) * 1024) + it*16 + row) * 64 + vf*16 + fr] =
          (f16)(oacc[vf][r] * id[r]);
    }
  if (fr == 0){
    #pragma unroll
    for (int r = 0; r < 4; r++){
      int row = g*4 + r;
      part_md[(size_t)(s*32 + bh) * 1024 + it*16 + row] = make_float2(mrun[r], den[r]);
    }
  }
}

// ---------------------------------------------------------------------------
// K5: out = combine(part) @ Wo + residual. Combine fused into A-staging:
// each staging thread merges its 16B chunk across the 2 j-splits using
// (m,den), writes LDS; MFMA loop unchanged. AO buffer eliminated.
__global__ __launch_bounds__(256) void k_out(
    const f16* __restrict__ part_o, const float2* __restrict__ part_md,
    const f16* __restrict__ WoT,
    const float* __restrict__ x, float* __restrict__ out){
  __shared__ f16 As[64*32], Bs[128*32];
  int bid = blockIdx.x;
  int mt = bid & 63, nt = bid >> 6;
  int m0 = mt << 6, n0 = nt << 7;
  int t = threadIdx.x, lane = t & 63, w = t >> 6;
  int wm = (w >> 1) << 5, wn = (w & 1) << 6;
  int fr = lane & 15, g = lane >> 4;
  f32x4 acc[2][4];
  #pragma unroll
  for (int i = 0; i < 2; i++)
    #pragma unroll
    for (int j = 0; j < 4; j++) acc[i][j] = (f32x4){0.f,0.f,0.f,0.f};

  // this thread's fixed A-staging row
  int row_l = t >> 2, part = t & 3;
  int grow = m0 + row_l;
  int b = grow >> 10, i = grow & 1023;

  for (int k0 = 0; k0 < 512; k0 += 32){
    // ---- A-staging with fused 2-way combine ----
    {
      int col0 = k0 + part*8;
      int h = col0 >> 6, d0 = col0 & 63;
      int bh = b*8 + h;
      float2 md0 = part_md[(size_t)bh * 1024 + i];
      float2 md1 = part_md[(size_t)(32 + bh) * 1024 + i];
      float M = fmaxf(md0.x, md1.x);
      float w0 = md0.y * exp2f((md0.x - M) * 1.44269504089f);
      float w1 = md1.y * exp2f((md1.x - M) * 1.44269504089f);
      float scl = 0.125f / (w0 + w1);
      f16x8 a0 = *(const f16x8*)(part_o + ((size_t)bh * 1024 + i) * 64 + d0);
      f16x8 a1 = *(const f16x8*)(part_o + ((size_t)(32 + bh) * 1024 + i) * 64 + d0);
      f16x8 av;
      #pragma unroll
      for (int dd = 0; dd < 8; dd++)
        av[dd] = (f16)(((float)a0[dd] * w0 + (float)a1[dd] * w1) * scl);
      *(f16x8*)&As[row_l*32 + part*8] = av;
    }
    // ---- B-staging (unchanged) ----
    #pragma unroll
    for (int q = 0; q < 2; q++){
      int c = ((q << 2) + w) * 64 + lane;
      int row = c >> 2, prt = c & 3;
      gld16(WoT + (size_t)(n0+row)*512 + k0 + prt*8, &Bs[((q<<2)+w)*512]);
    }
    __syncthreads();
    f16x8 af[2], bf_[4];
    #pragma unroll
    for (int mi = 0; mi < 2; mi++) af[mi]  = *(const f16x8*)&As[(wm + mi*16 + fr)*32 + g*8];
    #pragma unroll
    for (int ni = 0; ni < 4; ni++) bf_[ni] = *(const f16x8*)&Bs[(wn + ni*16 + fr)*32 + g*8];
    #pragma unroll
    for (int mi = 0; mi < 2; mi++)
      #pragma unroll
      for (int ni = 0; ni < 4; ni++)
        acc[mi][ni] = MFMAH(af[mi], bf_[ni], acc[mi][ni]);
    __syncthreads();
  }
  #pragma unroll
  for (int mi = 0; mi < 2; mi++)
    #pragma unroll
    for (int ni = 0; ni < 4; ni++)
      #pragma unroll
      for (int r = 0; r < 4; r++){
        size_t gm = m0 + wm + mi*16 + g*4 + r;
        size_t gn = n0 + wn + ni*16 + fr;
        out[gm*512 + gn] = acc[mi][ni][r] + x[gm*512 + gn];
      }
}

// ---------------------------------------------------------------------------
extern "C" void kernel_launch(void* const* d_in, const int* in_sizes, int n_in,
                              void* d_out, int out_size, void* d_ws, size_t ws_size,
                              hipStream_t stream){
  const float* xin   = (const float*)d_in[0];
  const float* edge  = (const float*)d_in[1];
  const float* mask  = (const float*)d_in[2];
  const float* gamma = (const float*)d_in[3];
  const float* beta  = (const float*)d_in[4];
  const float* Wq    = (const float*)d_in[5];
  const float* Wk    = (const float*)d_in[6];
  const float* Wv    = (const float*)d_in[7];
  const float* We    = (const float*)d_in[8];
  const float* Wo    = (const float*)d_in[9];
  float* out = (float*)d_out;

  f16* p   = (f16*)d_ws;
  f16* WT      = p;   p += 1536*512;
  f16* WoT     = p;   p += 512*512;
  f16* rf      = p;   p += 4096*512;
  f16* qf      = p;   p += 2097152;
  f16* kf      = p;   p += 2097152;
  f16* vT      = p;   p += 2097152;
  f16* biasP   = p;   p += 33554432;        // [bh][i][j] f16, 64 MB
  f16* part_o  = p;   p += 4194304;         // 2 x 32 x 1024 x 64
  float2* part_md = (float2*)p;             // 65536 float2

  k_prep <<<2048, 256, 0, stream>>>(Wq, Wk, Wv, Wo, xin, gamma, beta, WT, WoT, rf);
  k_bq   <<<4480, 256, 0, stream>>>(rf, WT, qf, kf, vT, edge, We, biasP);
  k_attn <<<1024, 256, 0, stream>>>(biasP, mask, qf, kf, vT, part_o, part_md);
  k_out  <<<256,  256, 0, stream>>>(part_o, part_md, WoT, xin, out);
}